// Round 3
// baseline (427.010 us; speedup 1.0000x reference)
//
#include <hip/hip_runtime.h>
#include <math.h>

#define NN 4096
#define DD 512
#define INV_TAU 5.0f
#define EPSV 1e-15f

typedef unsigned short u16;
typedef __attribute__((ext_vector_type(8))) short short8;
typedef __attribute__((ext_vector_type(4))) float f32x4;

__device__ __forceinline__ void gld16(const void* g, void* l) {
  __builtin_amdgcn_global_load_lds(
      (const __attribute__((address_space(1))) unsigned int*)g,
      (__attribute__((address_space(3))) unsigned int*)l, 16, 0, 0);
}

// counted-vmcnt barriers (T3/T4): N = one stage's worth of this wave's loads.
__device__ __forceinline__ void bar_vm5() {
  asm volatile("s_waitcnt vmcnt(5) lgkmcnt(0)\n\ts_barrier" ::: "memory");
}
__device__ __forceinline__ void bar_vm4() {
  asm volatile("s_waitcnt vmcnt(4) lgkmcnt(0)\n\ts_barrier" ::: "memory");
}
__device__ __forceinline__ void bar_vm2() {
  asm volatile("s_waitcnt vmcnt(2) lgkmcnt(0)\n\ts_barrier" ::: "memory");
}
__device__ __forceinline__ void bar_vm1() {
  asm volatile("s_waitcnt vmcnt(1) lgkmcnt(0)\n\ts_barrier" ::: "memory");
}
__device__ __forceinline__ void bar_vm0() {
  asm volatile("s_waitcnt vmcnt(0) lgkmcnt(0)\n\ts_barrier" ::: "memory");
}

__device__ __forceinline__ float bf2f(u16 u) {
  return __uint_as_float(((unsigned)u) << 16);
}
__device__ __forceinline__ u16 f2bf(float x) {  // RNE
  unsigned u = __float_as_uint(x);
  u += 0x7fff + ((u >> 16) & 1);
  return (u16)(u >> 16);
}

__device__ __forceinline__ float wave_sum(float v) {
#pragma unroll
  for (int o = 32; o > 0; o >>= 1) v += __shfl_down(v, o, 64);
  return v;
}

// coherent (agent-scope) load — safe for reading other XCDs' atomics in-kernel
__device__ __forceinline__ float ldz(const float* p) {
  return __hip_atomic_load(p, __ATOMIC_RELAXED, __HIP_MEMORY_SCOPE_AGENT);
}

// ------- node 1: fp32->bf16 convert (lw1|lw2|z1|z2) + colmean partials -------
// blocks [0,4608): convert; blocks [4608,4736): column-sum partials of z1,z2
// (32 rows each -> pc[128][512], plain writes). block0 zeroes ctr; blocks
// 0..127 zero zbf.
__global__ __launch_bounds__(256) void tobf16cm(
    const float* __restrict__ a, const float* __restrict__ b,
    const float* __restrict__ c, const float* __restrict__ d2,
    u16* __restrict__ o, float* __restrict__ pc1, float* __restrict__ pc2,
    float* __restrict__ zbf, int* __restrict__ ctr) {
  const int bid = blockIdx.x, tid = threadIdx.x;
  if (bid >= 4608) {  // colmean partials
    const int blk = bid - 4608;
    const int r0 = blk * 32;
    float a0 = 0.f, a1 = 0.f, c0 = 0.f, c1 = 0.f;
    for (int r = r0; r < r0 + 32; ++r) {
      const size_t ro = (size_t)r * DD;
      a0 += c[ro + tid];
      a1 += c[ro + 256 + tid];
      c0 += d2[ro + tid];
      c1 += d2[ro + 256 + tid];
    }
    pc1[blk * 512 + tid] = a0;
    pc1[blk * 512 + 256 + tid] = a1;
    pc2[blk * 512 + tid] = c0;
    pc2[blk * 512 + 256 + tid] = c1;
    return;
  }
  if (bid == 0 && tid == 0) ctr[0] = 0;
  if (bid < 128) zbf[bid * 256 + tid] = 0.f;
  const int i = bid * 256 + tid;
  int j = i;
  const float* s;
  if (j < 65536) {
    s = a + (size_t)j * 4;
  } else {
    j -= 65536;
    if (j < 65536) {
      s = b + (size_t)j * 4;
    } else {
      j -= 65536;
      if (j < 524288) {
        s = c + (size_t)j * 4;
      } else {
        j -= 524288;
        s = d2 + (size_t)j * 4;
      }
    }
  }
  float4 v = *(const float4*)s;
  unsigned long long pk = (unsigned long long)f2bf(v.x) |
                          ((unsigned long long)f2bf(v.y) << 16) |
                          ((unsigned long long)f2bf(v.z) << 32) |
                          ((unsigned long long)f2bf(v.w) << 48);
  *(unsigned long long*)&o[(size_t)i * 4] = pk;
}

// ------- node 2: MFMA NT GEMM (layer 1, PReLU), depth-3 counted-vmcnt -------
// (r2 kernel, correctness-proven) tile 128x64, 8 waves of 32x32, grid 512.
template <int ACT>
__global__ __launch_bounds__(512) void gemm_mfma(
    const u16* __restrict__ A, const u16* __restrict__ Bw,
    const float* __restrict__ bias, const float* __restrict__ alpha_p,
    u16* __restrict__ out) {
  __shared__ __align__(16) u16 sh[3 * 6144];
  const int tid = threadIdx.x, w = tid >> 6, lane = tid & 63;
  const int quad = lane >> 4, m16 = lane & 15;
  const int wi = w >> 1, wj = w & 1;
  const int bid = blockIdx.x;
  const int xcd = bid & 7, idx = bid >> 3;
  const int i0 = (4 * xcd + (idx & 3)) * 128;
  const int j0 = ((idx >> 2) & 7) * 64;
  const int bz = idx >> 5;
  const u16* Ab = A + (size_t)bz * ((size_t)NN * DD);
  u16* ob = out + (size_t)bz * ((size_t)NN * DD);
  const int roff =
      (m16 >> 1) * 64 + (((((m16 & 1) << 2) | quad) ^ (m16 >> 1)) * 8);
  const int st = (lane & 7) ^ (lane >> 3);
  const int srow = 2 * (lane >> 3) + (st >> 2);
  const int scol = (st & 3) * 8;
  const u16* gs = (w < 4) ? Ab : Bw;
  const int grow0 = ((w < 4) ? i0 + 2 * w * 16 : j0 + (w - 4) * 16) + srow;
  const int doff0 = (w < 4) ? 2 * w * 512 : 4096 + (w - 4) * 512;
  auto stage = [&](int bo, int k) {
    const int kn = k * 32;
    gld16(&gs[(size_t)grow0 * DD + kn + scol], sh + bo + doff0);
    if (w < 4)
      gld16(&gs[(size_t)(grow0 + 16) * DD + kn + scol], sh + bo + doff0 + 512);
  };
  stage(0, 0);
  stage(6144, 1);
  if (w < 4) bar_vm2(); else bar_vm1();
  f32x4 acc[2][2] = {};
  int ro = 0;
  for (int kc = 0; kc < 16; ++kc) {
    if (kc <= 13) {
      int so = ro + 12288;
      if (so >= 18432) so -= 18432;
      stage(so, kc + 2);
    }
    const u16* As = sh + ro;
    const u16* Bs = sh + ro + 4096;
    short8 ar[2], br[2];
#pragma unroll
    for (int s = 0; s < 2; ++s) {
      ar[s] = *(const short8*)&As[(wi * 32 + s * 16) * 32 + roff];
      br[s] = *(const short8*)&Bs[(wj * 32 + s * 16) * 32 + roff];
    }
    __builtin_amdgcn_s_setprio(1);
#pragma unroll
    for (int si = 0; si < 2; ++si)
#pragma unroll
      for (int sj = 0; sj < 2; ++sj)
        acc[si][sj] = __builtin_amdgcn_mfma_f32_16x16x32_bf16(
            ar[si], br[sj], acc[si][sj], 0, 0, 0);
    __builtin_amdgcn_s_setprio(0);
    if (kc <= 13) {
      if (w < 4) bar_vm2(); else bar_vm1();
    } else if (kc == 14) {
      bar_vm0();
    }
    ro += 6144;
    if (ro == 18432) ro = 0;
  }
  const float al = ACT ? alpha_p[0] : 0.f;
#pragma unroll
  for (int si = 0; si < 2; ++si)
#pragma unroll
    for (int sj = 0; sj < 2; ++sj) {
      const int col = j0 + wj * 32 + sj * 16 + m16;
      const float bv = bias[col];
#pragma unroll
      for (int r = 0; r < 4; ++r) {
        const int row = i0 + wi * 32 + si * 16 + quad * 4 + r;
        float x = acc[si][sj][r] + bv;
        if (ACT) x = (x >= 0.f) ? x : al * x;
        ob[(size_t)row * DD + col] = f2bf(x);
      }
    }
}

// ------- node 3: GEMM layer 2 with FUSED row L2-normalize -------------------
// tile 32 rows x 512 cols (full row), grid 256 (=1/CU), 8 waves: wave w owns
// cols [w*64, w*64+64). LDS/kc: B=W2 512x32 (32 KB) + A 32x32 (2 KB), depth 3.
// Waves 0-1 stage 5 gld16/kc (4 B-groups + 1 A-group), waves 2-7 stage 4.
__global__ __launch_bounds__(512) void gemm2n(const u16* __restrict__ Ain,
                                              const u16* __restrict__ Bw,
                                              const float* __restrict__ bias,
                                              u16* __restrict__ outn) {
  extern __shared__ __align__(16) u16 shb[];  // 3 * 17408 u16 = 104448 B
  const int BUF = 17408;
  const int tid = threadIdx.x, w = tid >> 6, lane = tid & 63;
  const int quad = lane >> 4, m16 = lane & 15;
  const int bid = blockIdx.x;
  const int bz = bid >> 7, band = bid & 127;
  const int i0 = band * 32;
  const u16* Ab = Ain + (size_t)bz * ((size_t)NN * DD);
  u16* ob = outn + (size_t)bz * ((size_t)NN * DD);
  const int roff =
      (m16 >> 1) * 64 + (((((m16 & 1) << 2) | quad) ^ (m16 >> 1)) * 8);
  const int st = (lane & 7) ^ (lane >> 3);
  const int srow = 2 * (lane >> 3) + (st >> 2);
  const int scol = (st & 3) * 8;
  const int g0 = w * 4;
  auto stage = [&](int bo, int k) {
    const int kn = k * 32;
#pragma unroll
    for (int q = 0; q < 4; ++q) {
      const int grow = (g0 + q) * 16 + srow;
      gld16(&Bw[(size_t)grow * DD + kn + scol], shb + bo + (g0 + q) * 512);
    }
    if (w < 2) {
      const int grow = i0 + w * 16 + srow;
      gld16(&Ab[(size_t)grow * DD + kn + scol], shb + bo + 16384 + w * 512);
    }
  };
  stage(0, 0);
  stage(BUF, 1);
  if (w < 2) bar_vm5(); else bar_vm4();
  f32x4 acc[2][4] = {};
  int ro = 0;
  for (int kc = 0; kc < 16; ++kc) {
    if (kc <= 13) {
      int so = ro + 2 * BUF;
      if (so >= 3 * BUF) so -= 3 * BUF;
      stage(so, kc + 2);
    }
    const u16* Bs = shb + ro;
    const u16* As = shb + ro + 16384;
    short8 ar[2], br[4];
#pragma unroll
    for (int s = 0; s < 2; ++s)
      ar[s] = *(const short8*)&As[(s * 16) * 32 + roff];
#pragma unroll
    for (int s = 0; s < 4; ++s)
      br[s] = *(const short8*)&Bs[(w * 64 + s * 16) * 32 + roff];
    __builtin_amdgcn_s_setprio(1);
#pragma unroll
    for (int si = 0; si < 2; ++si)
#pragma unroll
      for (int sj = 0; sj < 4; ++sj)
        acc[si][sj] = __builtin_amdgcn_mfma_f32_16x16x32_bf16(
            ar[si], br[sj], acc[si][sj], 0, 0, 0);
    __builtin_amdgcn_s_setprio(0);
    if (kc <= 13) {
      if (w < 2) bar_vm5(); else bar_vm4();
    } else if (kc == 14) {
      bar_vm0();
    }
    ro += BUF;
    if (ro == 3 * BUF) ro = 0;
  }
  // epilogue: +bias, row sumsq over full 512 cols, normalize, store bf16.
  float ss[2][4] = {};
#pragma unroll
  for (int si = 0; si < 2; ++si)
#pragma unroll
    for (int sj = 0; sj < 4; ++sj) {
      const float bv = bias[w * 64 + sj * 16 + m16];
#pragma unroll
      for (int r = 0; r < 4; ++r) {
        const float x = acc[si][sj][r] + bv;
        acc[si][sj][r] = x;
        ss[si][r] = fmaf(x, x, ss[si][r]);
      }
    }
#pragma unroll
  for (int si = 0; si < 2; ++si)
#pragma unroll
    for (int r = 0; r < 4; ++r) {
#pragma unroll
      for (int o = 1; o < 16; o <<= 1) ss[si][r] += __shfl_xor(ss[si][r], o, 64);
    }
  float* part = (float*)(shb + BUF);  // [32][8] (buf1 area — dead, see r3 note)
  float* invn = part + 256;           // [32]
  if (m16 == 0) {
#pragma unroll
    for (int si = 0; si < 2; ++si)
#pragma unroll
      for (int r = 0; r < 4; ++r)
        part[(si * 16 + quad * 4 + r) * 8 + w] = ss[si][r];
  }
  __syncthreads();
  if (tid < 32) {
    float s = 0.f;
#pragma unroll
    for (int q = 0; q < 8; ++q) s += part[tid * 8 + q];
    invn[tid] = 1.f / fmaxf(sqrtf(s), 1e-12f);
  }
  __syncthreads();
#pragma unroll
  for (int si = 0; si < 2; ++si)
#pragma unroll
    for (int sj = 0; sj < 4; ++sj) {
      const int col = w * 64 + sj * 16 + m16;
#pragma unroll
      for (int r = 0; r < 4; ++r) {
        const int r32 = si * 16 + quad * 4 + r;
        ob[(size_t)(i0 + r32) * DD + col] = f2bf(acc[si][sj][r] * invn[r32]);
      }
    }
}

// ------- node 4: whole global-projector chain, one block per batch ----------
__global__ __launch_bounds__(1024) void mv_chain(
    const float* __restrict__ pc1, const float* __restrict__ pc2,
    const float* __restrict__ gw1, const float* __restrict__ gb1,
    const float* __restrict__ ga, const float* __restrict__ gw2,
    const float* __restrict__ gb2, const float* __restrict__ W,
    float* __restrict__ summ1, float* __restrict__ summ2) {
  const int bz = blockIdx.x;
  const float* pc = bz ? pc2 : pc1;
  float* summ = bz ? summ2 : summ1;
  __shared__ float sv[512], tv[512], hv[512];
  const int tid = threadIdx.x;
  if (tid < 512) {
    float a = 0.f;
    for (int b = 0; b < 128; ++b) a += pc[b * 512 + tid];
    sv[tid] = a * (1.f / NN);
  }
  __syncthreads();
  const int w = tid >> 6, lane = tid & 63;
  // phase 1: tv = prelu(gw1 @ sv + gb1); 16 waves x 32 rows, 4-row batches
  for (int rq = 0; rq < 8; ++rq) {
    const int row = w * 32 + rq * 4;
    float a0 = 0.f, a1 = 0.f, a2 = 0.f, a3 = 0.f;
#pragma unroll
    for (int t = 0; t < 8; ++t) {
      const float x = sv[lane + 64 * t];
      a0 = fmaf(gw1[(size_t)(row + 0) * DD + lane + 64 * t], x, a0);
      a1 = fmaf(gw1[(size_t)(row + 1) * DD + lane + 64 * t], x, a1);
      a2 = fmaf(gw1[(size_t)(row + 2) * DD + lane + 64 * t], x, a2);
      a3 = fmaf(gw1[(size_t)(row + 3) * DD + lane + 64 * t], x, a3);
    }
    a0 = wave_sum(a0); a1 = wave_sum(a1); a2 = wave_sum(a2); a3 = wave_sum(a3);
    if (lane == 0) {
      const float al = ga[0];
      float v0 = a0 + gb1[row + 0], v1 = a1 + gb1[row + 1];
      float v2 = a2 + gb1[row + 2], v3 = a3 + gb1[row + 3];
      tv[row + 0] = (v0 >= 0.f) ? v0 : al * v0;
      tv[row + 1] = (v1 >= 0.f) ? v1 : al * v1;
      tv[row + 2] = (v2 >= 0.f) ? v2 : al * v2;
      tv[row + 3] = (v3 >= 0.f) ? v3 : al * v3;
    }
  }
  __syncthreads();
  // phase 2: hv = gw2 @ tv + gb2
  for (int rq = 0; rq < 8; ++rq) {
    const int row = w * 32 + rq * 4;
    float a0 = 0.f, a1 = 0.f, a2 = 0.f, a3 = 0.f;
#pragma unroll
    for (int t = 0; t < 8; ++t) {
      const float x = tv[lane + 64 * t];
      a0 = fmaf(gw2[(size_t)(row + 0) * DD + lane + 64 * t], x, a0);
      a1 = fmaf(gw2[(size_t)(row + 1) * DD + lane + 64 * t], x, a1);
      a2 = fmaf(gw2[(size_t)(row + 2) * DD + lane + 64 * t], x, a2);
      a3 = fmaf(gw2[(size_t)(row + 3) * DD + lane + 64 * t], x, a3);
    }
    a0 = wave_sum(a0); a1 = wave_sum(a1); a2 = wave_sum(a2); a3 = wave_sum(a3);
    if (lane == 0) {
      hv[row + 0] = a0 + gb2[row + 0];
      hv[row + 1] = a1 + gb2[row + 1];
      hv[row + 2] = a2 + gb2[row + 2];
      hv[row + 3] = a3 + gb2[row + 3];
    }
  }
  __syncthreads();
  // phase 3: summ = W @ hv
  for (int rq = 0; rq < 8; ++rq) {
    const int row = w * 32 + rq * 4;
    float a0 = 0.f, a1 = 0.f, a2 = 0.f, a3 = 0.f;
#pragma unroll
    for (int t = 0; t < 8; ++t) {
      const float x = hv[lane + 64 * t];
      a0 = fmaf(W[(size_t)(row + 0) * DD + lane + 64 * t], x, a0);
      a1 = fmaf(W[(size_t)(row + 1) * DD + lane + 64 * t], x, a1);
      a2 = fmaf(W[(size_t)(row + 2) * DD + lane + 64 * t], x, a2);
      a3 = fmaf(W[(size_t)(row + 3) * DD + lane + 64 * t], x, a3);
    }
    a0 = wave_sum(a0); a1 = wave_sum(a1); a2 = wave_sum(a2); a3 = wave_sum(a3);
    if (lane == 0) {
      summ[row + 0] = a0;
      summ[row + 1] = a1;
      summ[row + 2] = a2;
      summ[row + 3] = a3;
    }
  }
}

// ------- node 5: paired sigmoid/log reduce -> per-block partials ------------
__global__ __launch_bounds__(256) void logsigp(
    const float* __restrict__ z1, const float* __restrict__ z2,
    const float* __restrict__ sm1, const float* __restrict__ sm2,
    float* __restrict__ plsP, float* __restrict__ plsN) {
  const int ch = blockIdx.y;
  const float* z = ch ? z2 : z1;
  const float* sp = ch ? sm2 : sm1;
  const float* sn = ch ? sm1 : sm2;
  const int lane = threadIdx.x & 63;
  const int wid = threadIdx.x >> 6;
  const int row = blockIdx.x * 4 + wid;
  float dp = 0.f, dn = 0.f;
#pragma unroll
  for (int t = 0; t < 8; ++t) {
    const float zv = z[(size_t)row * DD + lane + 64 * t];
    dp = fmaf(zv, sp[lane + 64 * t], dp);
    dn = fmaf(zv, sn[lane + 64 * t], dn);
  }
  dp = wave_sum(dp);
  dn = wave_sum(dn);
  __shared__ float bp[4], bn[4];
  if (lane == 0) {
    const float sg = 1.f / (1.f + __expf(-dp));
    bp[wid] = -logf(sg + EPSV);
    const float sg2 = 1.f / (1.f + __expf(-dn));
    bn[wid] = -logf(1.f - sg2 + EPSV);
  }
  __syncthreads();
  if (threadIdx.x == 0) {
    plsP[ch * 1024 + blockIdx.x] = bp[0] + bp[1] + bp[2] + bp[3];
    plsN[ch * 1024 + blockIdx.x] = bn[0] + bn[1] + bn[2] + bn[3];
  }
}

// ------- node 6: fused similarity + LAST-BLOCK finalize (lfin+combine) ------
// K-loop identical to r1/r2 (proven). zb: [r11,r11m,r12,r12m,c12,c12m,c22,
// c22m] x NN.
__global__ __launch_bounds__(512) void sim_mfma(
    const u16* __restrict__ na, const u16* __restrict__ nb,
    const int* __restrict__ mask, float* __restrict__ zb,
    int* __restrict__ ctr, const float* __restrict__ plsP,
    const float* __restrict__ plsN, float* __restrict__ out) {
  extern __shared__ __align__(16) u16 shm[];  // 3 * 4 * 4096 u16 = 96 KiB
  const int tid = threadIdx.x;
  const int w = tid >> 6, lane = tid & 63;
  const int quad = lane >> 4, m16 = lane & 15;
  const int ig = w & 3, jh = w >> 2;
  const int i0 = blockIdx.y * 128, j0 = blockIdx.x * 128;
  const int roff =
      (m16 >> 1) * 64 + (((((m16 & 1) << 2) | quad) ^ (m16 >> 1)) * 8);
  const int st = (lane & 7) ^ (lane >> 3);
  const int srow = 2 * (lane >> 3) + (st >> 2);
  const int scol = (st & 3) * 8;
  const int p = w >> 1, rh = (w & 1) * 64;
  const u16* gs = (p & 1) ? nb : na;
  const int gr = ((p < 2) ? i0 : j0) + rh + srow;
  u16* dst0 = shm + p * 4096 + rh * 32;
  auto stage = [&](int bo, int k) {
    const int kn = k * 32;
#pragma unroll
    for (int rr = 0; rr < 64; rr += 16)
      gld16(&gs[(size_t)(gr + rr) * DD + kn + scol], dst0 + bo + rr * 32);
  };
  stage(0, 0);
  stage(16384, 1);
  bar_vm4();
  f32x4 a11[2][4] = {}, a12[2][4] = {}, a22[2][4] = {};
  int ro = 0;
  for (int kc = 0; kc < 16; ++kc) {
    if (kc <= 13) {
      int so = ro + 32768;
      if (so >= 49152) so -= 49152;
      stage(so, kc + 2);
    }
    const u16* Ai = shm + ro;
    const u16* Bi = shm + ro + 4096;
    const u16* Aj = shm + ro + 8192;
    const u16* Bj = shm + ro + 12288;
    short8 ai0 = *(const short8*)&Ai[(ig * 32) * 32 + roff];
    short8 ai1 = *(const short8*)&Ai[(ig * 32 + 16) * 32 + roff];
    short8 bi0 = *(const short8*)&Bi[(ig * 32) * 32 + roff];
    short8 bi1 = *(const short8*)&Bi[(ig * 32 + 16) * 32 + roff];
#pragma unroll
    for (int c = 0; c < 4; ++c) {
      short8 aj = *(const short8*)&Aj[(jh * 64 + c * 16) * 32 + roff];
      short8 bj = *(const short8*)&Bj[(jh * 64 + c * 16) * 32 + roff];
      __builtin_amdgcn_s_setprio(1);
      a11[0][c] = __builtin_amdgcn_mfma_f32_16x16x32_bf16(ai0, aj, a11[0][c], 0, 0, 0);
      a11[1][c] = __builtin_amdgcn_mfma_f32_16x16x32_bf16(ai1, aj, a11[1][c], 0, 0, 0);
      a12[0][c] = __builtin_amdgcn_mfma_f32_16x16x32_bf16(ai0, bj, a12[0][c], 0, 0, 0);
      a12[1][c] = __builtin_amdgcn_mfma_f32_16x16x32_bf16(ai1, bj, a12[1][c], 0, 0, 0);
      a22[0][c] = __builtin_amdgcn_mfma_f32_16x16x32_bf16(bi0, bj, a22[0][c], 0, 0, 0);
      a22[1][c] = __builtin_amdgcn_mfma_f32_16x16x32_bf16(bi1, bj, a22[1][c], 0, 0, 0);
      __builtin_amdgcn_s_setprio(0);
    }
    if (kc <= 13) bar_vm4();
    else if (kc == 14) bar_vm0();
    ro += 16384;
    if (ro == 49152) ro = 0;
  }
  float* rred = (float*)(shm + 16384);  // [4][128] row stats (buf1: dead)
  float* cred = rred + 512;             // [4][128] col stats
  rred[tid] = 0.f;
  rred[tid + 512] = 0.f;
  __syncthreads();
  float rs11[2][4] = {}, rm11[2][4] = {}, rs12[2][4] = {}, rm12[2][4] = {};
  float cs12[4] = {}, cm12[4] = {}, cs22[4] = {}, cm22[4] = {};
#pragma unroll
  for (int t = 0; t < 2; ++t)
#pragma unroll
    for (int c = 0; c < 4; ++c) {
      const int gj = j0 + jh * 64 + c * 16 + m16;
#pragma unroll
      for (int r = 0; r < 4; ++r) {
        const int gi = i0 + ig * 32 + t * 16 + quad * 4 + r;
        const float mv = (float)mask[(size_t)gi * NN + gj];
        const float e11 = __expf(a11[t][c][r] * INV_TAU);
        const float e12 = __expf(a12[t][c][r] * INV_TAU);
        const float e22 = __expf(a22[t][c][r] * INV_TAU);
        rs11[t][r] += e11;
        rm11[t][r] += e11 * mv;
        rs12[t][r] += e12;
        rm12[t][r] += e12 * mv;
        cs12[c] += e12;
        cm12[c] += e12 * mv;
        cs22[c] += e22;
        cm22[c] += e22 * mv;
      }
    }
#pragma unroll
  for (int t = 0; t < 2; ++t)
#pragma unroll
    for (int r = 0; r < 4; ++r) {
      float v0 = rs11[t][r], v1 = rm11[t][r], v2 = rs12[t][r], v3 = rm12[t][r];
#pragma unroll
      for (int o = 1; o < 16; o <<= 1) {
        v0 += __shfl_xor(v0, o, 64);
        v1 += __shfl_xor(v1, o, 64);
        v2 += __shfl_xor(v2, o, 64);
        v3 += __shfl_xor(v3, o, 64);
      }
      if (m16 == 0) {
        const int il = ig * 32 + t * 16 + quad * 4 + r;
        atomicAdd(&rred[0 * 128 + il], v0);
        atomicAdd(&rred[1 * 128 + il], v1);
        atomicAdd(&rred[2 * 128 + il], v2);
        atomicAdd(&rred[3 * 128 + il], v3);
      }
    }
#pragma unroll
  for (int c = 0; c < 4; ++c) {
    float v0 = cs12[c], v1 = cm12[c], v2 = cs22[c], v3 = cm22[c];
    v0 += __shfl_xor(v0, 16, 64); v0 += __shfl_xor(v0, 32, 64);
    v1 += __shfl_xor(v1, 16, 64); v1 += __shfl_xor(v1, 32, 64);
    v2 += __shfl_xor(v2, 16, 64); v2 += __shfl_xor(v2, 32, 64);
    v3 += __shfl_xor(v3, 16, 64); v3 += __shfl_xor(v3, 32, 64);
    if (lane < 16) {
      const int jl = jh * 64 + c * 16 + lane;
      atomicAdd(&cred[0 * 128 + jl], v0);
      atomicAdd(&cred[1 * 128 + jl], v1);
      atomicAdd(&cred[2 * 128 + jl], v2);
      atomicAdd(&cred[3 * 128 + jl], v3);
    }
  }
  __syncthreads();
  if (tid < 128) {
#pragma unroll
    for (int q = 0; q < 4; ++q)
      atomicAdd(&zb[q * NN + i0 + tid], rred[q * 128 + tid]);
  } else if (tid < 256) {
    const int jl = tid - 128;
#pragma unroll
    for (int q = 0; q < 4; ++q)
      atomicAdd(&zb[(4 + q) * NN + j0 + jl], cred[q * 128 + jl]);
  }
  // ---- last block: local InfoNCE finalize + logsig partial reduce + combine
  __threadfence();
  __syncthreads();
  __shared__ int lastf_s;
  if (tid == 0) lastf_s = (atomicAdd(ctr, 1) == 1023) ? 1 : 0;
  __syncthreads();
  if (!lastf_s) return;
  __threadfence();
  float S1 = 0.f, S2 = 0.f;
#pragma unroll
  for (int k = 0; k < 8; ++k) {
    const int i = tid + k * 512;
    const float r11 = ldz(&zb[i]), r11m = ldz(&zb[NN + i]);
    const float r12 = ldz(&zb[2 * NN + i]), r12m = ldz(&zb[3 * NN + i]);
    const float c12 = ldz(&zb[4 * NN + i]), c12m = ldz(&zb[5 * NN + i]);
    const float c22 = ldz(&zb[6 * NN + i]), c22m = ldz(&zb[7 * NN + i]);
    S1 += -logf(r12m / (r11 + r12 - r11m));
    S2 += -logf(c12m / (c22 + c12 - c22m));
  }
  float G = plsP[tid] + plsP[tid + 512] + plsP[tid + 1024] + plsP[tid + 1536] +
            plsN[tid] + plsN[tid + 512] + plsN[tid + 1024] + plsN[tid + 1536];
  S1 = wave_sum(S1);
  S2 = wave_sum(S2);
  G = wave_sum(G);
  __shared__ float fr[3][8];
  if (lane == 0) { fr[0][w] = S1; fr[1][w] = S2; fr[2][w] = G; }
  __syncthreads();
  if (tid == 0) {
    float s1t = 0.f, s2t = 0.f, gt = 0.f;
    for (int q = 0; q < 8; ++q) {
      s1t += fr[0][q];
      s2t += fr[1][q];
      gt += fr[2][q];
    }
    const float local = 0.5f * (s1t + s2t) * (1.f / NN);
    const float glob = 0.25f * gt * (1.f / NN);
    out[0] = 0.5f * local + 0.5f * glob;
  }
}

extern "C" void kernel_launch(void* const* d_in, const int* in_sizes, int n_in,
                              void* d_out, int out_size, void* d_ws,
                              size_t ws_size, hipStream_t stream) {
  const float* z1 = (const float*)d_in[0];
  const float* z2 = (const float*)d_in[1];
  const float* lw1 = (const float*)d_in[2];
  const float* lb1 = (const float*)d_in[3];
  const float* la = (const float*)d_in[4];
  const float* lw2 = (const float*)d_in[5];
  const float* lb2 = (const float*)d_in[6];
  const float* gw1 = (const float*)d_in[7];
  const float* gb1 = (const float*)d_in[8];
  const float* ga = (const float*)d_in[9];
  const float* gw2 = (const float*)d_in[10];
  const float* gb2 = (const float*)d_in[11];
  const float* W = (const float*)d_in[12];
  const int* mask = (const int*)d_in[13];
  float* out = (float*)d_out;

  static bool attr_set = false;
  if (!attr_set) {
    (void)hipFuncSetAttribute(reinterpret_cast<const void*>(sim_mfma),
                              hipFuncAttributeMaxDynamicSharedMemorySize,
                              98304);
    (void)hipFuncSetAttribute(reinterpret_cast<const void*>(gemm2n),
                              hipFuncAttributeMaxDynamicSharedMemorySize,
                              104448);
    attr_set = true;
  }

  const size_t ND = (size_t)NN * DD;
  u16* W1b = (u16*)d_ws;                  // [512*512]
  u16* W2b = W1b + 512 * 512;             // [512*512]
  u16* Ab = W1b + 2 * 512 * 512;          // [2][N*D] bf16 z -> later normalized
  u16* Bb = Ab + 2 * ND;                  // [2][N*D] bf16 act1
  float* zbf = (float*)(Bb + 2 * ND);     // 8*NN
  float* pc1 = zbf + 8 * NN;              // [128][512]
  float* pc2 = pc1 + 128 * 512;           // [128][512]
  float* summ1 = pc2 + 128 * 512;         // 512
  float* summ2 = summ1 + 512;             // 512
  float* plsP = summ2 + 512;              // 2048
  float* plsN = plsP + 2048;              // 2048
  int* ctr = (int*)(plsN + 2048);

  dim3 blk(256);
  // 1) convert lw1|lw2|z1|z2 to bf16 + colmean partials + zero zbf/ctr
  tobf16cm<<<4736, blk, 0, stream>>>(lw1, lw2, z1, z2, W1b, pc1, pc2, zbf, ctr);
  // 2) layer-1 GEMM (PReLU)
  gemm_mfma<1><<<512, dim3(512), 0, stream>>>(Ab, W1b, lb1, la, Bb);
  // 3) layer-2 GEMM + fused row L2-normalize -> Ab (na|nb)
  gemm2n<<<256, dim3(512), 104448, stream>>>(Bb, W2b, lb2, Ab);
  // 4) global projector chain (2 blocks, one per batch)
  mv_chain<<<2, dim3(1024), 0, stream>>>(pc1, pc2, gw1, gb1, ga, gw2, gb2, W,
                                         summ1, summ2);
  // 5) logsig partials (needs summ only)
  logsigp<<<dim3(1024, 2), blk, 0, stream>>>(z1, z2, summ1, summ2, plsP, plsN);
  // 6) fused similarity; last block finalizes everything -> out[0]
  sim_mfma<<<dim3(32, 32), dim3(512), 98304, stream>>>(Ab, Ab + ND, mask, zbf,
                                                       ctr, plsP, plsN, out);
}

// Round 4
// 302.606 us; speedup vs baseline: 1.4111x; 1.4111x over previous
//
#include <hip/hip_runtime.h>
#include <math.h>

#define NN 4096
#define DD 512
#define INV_TAU 5.0f
#define EPSV 1e-15f

typedef unsigned short u16;
typedef __attribute__((ext_vector_type(8))) short short8;
typedef __attribute__((ext_vector_type(4))) float f32x4;

__device__ __forceinline__ void gld16(const void* g, void* l) {
  __builtin_amdgcn_global_load_lds(
      (const __attribute__((address_space(1))) unsigned int*)g,
      (__attribute__((address_space(3))) unsigned int*)l, 16, 0, 0);
}

// counted-vmcnt barriers (T3/T4)
__device__ __forceinline__ void bar_vm4() {
  asm volatile("s_waitcnt vmcnt(4) lgkmcnt(0)\n\ts_barrier" ::: "memory");
}
__device__ __forceinline__ void bar_vm2() {
  asm volatile("s_waitcnt vmcnt(2) lgkmcnt(0)\n\ts_barrier" ::: "memory");
}
__device__ __forceinline__ void bar_vm1() {
  asm volatile("s_waitcnt vmcnt(1) lgkmcnt(0)\n\ts_barrier" ::: "memory");
}
__device__ __forceinline__ void bar_vm0() {
  asm volatile("s_waitcnt vmcnt(0) lgkmcnt(0)\n\ts_barrier" ::: "memory");
}

__device__ __forceinline__ float bf2f(u16 u) {
  return __uint_as_float(((unsigned)u) << 16);
}
__device__ __forceinline__ u16 f2bf(float x) {  // RNE
  unsigned u = __float_as_uint(x);
  u += 0x7fff + ((u >> 16) & 1);
  return (u16)(u >> 16);
}

__device__ __forceinline__ float wave_sum(float v) {
#pragma unroll
  for (int o = 32; o > 0; o >>= 1) v += __shfl_down(v, o, 64);
  return v;
}

// ------- node 1: fp32->bf16 convert (lw1|lw2|z1|z2) + colmean partials -------
// blocks [0,4608): convert; blocks [4608,4736): column-sum partials of z1,z2
// (32 rows each -> pc[128][512], plain writes). blocks 0..127 zero zbf.
__global__ __launch_bounds__(256) void tobf16cm(
    const float* __restrict__ a, const float* __restrict__ b,
    const float* __restrict__ c, const float* __restrict__ d2,
    u16* __restrict__ o, float* __restrict__ pc1, float* __restrict__ pc2,
    float* __restrict__ zbf) {
  const int bid = blockIdx.x, tid = threadIdx.x;
  if (bid >= 4608) {  // colmean partials
    const int blk = bid - 4608;
    const int r0 = blk * 32;
    float a0 = 0.f, a1 = 0.f, c0 = 0.f, c1 = 0.f;
    for (int r = r0; r < r0 + 32; ++r) {
      const size_t ro = (size_t)r * DD;
      a0 += c[ro + tid];
      a1 += c[ro + 256 + tid];
      c0 += d2[ro + tid];
      c1 += d2[ro + 256 + tid];
    }
    pc1[blk * 512 + tid] = a0;
    pc1[blk * 512 + 256 + tid] = a1;
    pc2[blk * 512 + tid] = c0;
    pc2[blk * 512 + 256 + tid] = c1;
    return;
  }
  if (bid < 128) zbf[bid * 256 + tid] = 0.f;
  const int i = bid * 256 + tid;
  int j = i;
  const float* s;
  if (j < 65536) {
    s = a + (size_t)j * 4;
  } else {
    j -= 65536;
    if (j < 65536) {
      s = b + (size_t)j * 4;
    } else {
      j -= 65536;
      if (j < 524288) {
        s = c + (size_t)j * 4;
      } else {
        j -= 524288;
        s = d2 + (size_t)j * 4;
      }
    }
  }
  float4 v = *(const float4*)s;
  unsigned long long pk = (unsigned long long)f2bf(v.x) |
                          ((unsigned long long)f2bf(v.y) << 16) |
                          ((unsigned long long)f2bf(v.z) << 32) |
                          ((unsigned long long)f2bf(v.w) << 48);
  *(unsigned long long*)&o[(size_t)i * 4] = pk;
}

// ------- nodes 2-3: MFMA NT GEMM, depth-3 counted-vmcnt (proven r2/r3) ------
// tile 128x64, 8 waves of 32x32, grid 512 (2 blocks/CU, 16 waves/CU).
template <int ACT>
__global__ __launch_bounds__(512) void gemm_mfma(
    const u16* __restrict__ A, const u16* __restrict__ Bw,
    const float* __restrict__ bias, const float* __restrict__ alpha_p,
    u16* __restrict__ out) {
  __shared__ __align__(16) u16 sh[3 * 6144];
  const int tid = threadIdx.x, w = tid >> 6, lane = tid & 63;
  const int quad = lane >> 4, m16 = lane & 15;
  const int wi = w >> 1, wj = w & 1;
  const int bid = blockIdx.x;
  const int xcd = bid & 7, idx = bid >> 3;
  const int i0 = (4 * xcd + (idx & 3)) * 128;
  const int j0 = ((idx >> 2) & 7) * 64;
  const int bz = idx >> 5;
  const u16* Ab = A + (size_t)bz * ((size_t)NN * DD);
  u16* ob = out + (size_t)bz * ((size_t)NN * DD);
  const int roff =
      (m16 >> 1) * 64 + (((((m16 & 1) << 2) | quad) ^ (m16 >> 1)) * 8);
  const int st = (lane & 7) ^ (lane >> 3);
  const int srow = 2 * (lane >> 3) + (st >> 2);
  const int scol = (st & 3) * 8;
  const u16* gs = (w < 4) ? Ab : Bw;
  const int grow0 = ((w < 4) ? i0 + 2 * w * 16 : j0 + (w - 4) * 16) + srow;
  const int doff0 = (w < 4) ? 2 * w * 512 : 4096 + (w - 4) * 512;
  auto stage = [&](int bo, int k) {
    const int kn = k * 32;
    gld16(&gs[(size_t)grow0 * DD + kn + scol], sh + bo + doff0);
    if (w < 4)
      gld16(&gs[(size_t)(grow0 + 16) * DD + kn + scol], sh + bo + doff0 + 512);
  };
  stage(0, 0);
  stage(6144, 1);
  if (w < 4) bar_vm2(); else bar_vm1();
  f32x4 acc[2][2] = {};
  int ro = 0;
  for (int kc = 0; kc < 16; ++kc) {
    if (kc <= 13) {
      int so = ro + 12288;
      if (so >= 18432) so -= 18432;
      stage(so, kc + 2);
    }
    const u16* As = sh + ro;
    const u16* Bs = sh + ro + 4096;
    short8 ar[2], br[2];
#pragma unroll
    for (int s = 0; s < 2; ++s) {
      ar[s] = *(const short8*)&As[(wi * 32 + s * 16) * 32 + roff];
      br[s] = *(const short8*)&Bs[(wj * 32 + s * 16) * 32 + roff];
    }
    __builtin_amdgcn_s_setprio(1);
#pragma unroll
    for (int si = 0; si < 2; ++si)
#pragma unroll
      for (int sj = 0; sj < 2; ++sj)
        acc[si][sj] = __builtin_amdgcn_mfma_f32_16x16x32_bf16(
            ar[si], br[sj], acc[si][sj], 0, 0, 0);
    __builtin_amdgcn_s_setprio(0);
    if (kc <= 13) {
      if (w < 4) bar_vm2(); else bar_vm1();
    } else if (kc == 14) {
      bar_vm0();
    }
    ro += 6144;
    if (ro == 18432) ro = 0;
  }
  const float al = ACT ? alpha_p[0] : 0.f;
#pragma unroll
  for (int si = 0; si < 2; ++si)
#pragma unroll
    for (int sj = 0; sj < 2; ++sj) {
      const int col = j0 + wj * 32 + sj * 16 + m16;
      const float bv = bias[col];
#pragma unroll
      for (int r = 0; r < 4; ++r) {
        const int row = i0 + wi * 32 + si * 16 + quad * 4 + r;
        float x = acc[si][sj][r] + bv;
        if (ACT) x = (x >= 0.f) ? x : al * x;
        ob[(size_t)row * DD + col] = f2bf(x);
      }
    }
}

// ------- node 4: row-wise L2 normalize, one wave per row (proven r2) --------
__global__ __launch_bounds__(256) void rownorm_bf16(const u16* __restrict__ h,
                                                    u16* __restrict__ o) {
  const int tid = threadIdx.x;
  const int row = blockIdx.x * 4 + (tid >> 6);
  const int lane = tid & 63;
  const size_t base = (size_t)row * DD + lane * 8;
  short8 v = *(const short8*)&h[base];
  float f[8];
  float s = 0.f;
#pragma unroll
  for (int j = 0; j < 8; ++j) {
    f[j] = bf2f((u16)v[j]);
    s += f[j] * f[j];
  }
  s = wave_sum(s);
  const float inv = 1.f / fmaxf(sqrtf(__shfl(s, 0, 64)), 1e-12f);
  short8 r;
#pragma unroll
  for (int j = 0; j < 8; ++j) r[j] = (short)f2bf(f[j] * inv);
  *(short8*)&o[base] = r;
}

// ------- node 5: whole global-projector chain, one block per batch ----------
__global__ __launch_bounds__(1024) void mv_chain(
    const float* __restrict__ pc1, const float* __restrict__ pc2,
    const float* __restrict__ gw1, const float* __restrict__ gb1,
    const float* __restrict__ ga, const float* __restrict__ gw2,
    const float* __restrict__ gb2, const float* __restrict__ W,
    float* __restrict__ summ1, float* __restrict__ summ2) {
  const int bz = blockIdx.x;
  const float* pc = bz ? pc2 : pc1;
  float* summ = bz ? summ2 : summ1;
  __shared__ float sv[512], tv[512], hv[512];
  const int tid = threadIdx.x;
  if (tid < 512) {
    float a = 0.f;
    for (int b = 0; b < 128; ++b) a += pc[b * 512 + tid];
    sv[tid] = a * (1.f / NN);
  }
  __syncthreads();
  const int w = tid >> 6, lane = tid & 63;
  for (int rq = 0; rq < 8; ++rq) {  // phase 1: tv = prelu(gw1 @ sv + gb1)
    const int row = w * 32 + rq * 4;
    float a0 = 0.f, a1 = 0.f, a2 = 0.f, a3 = 0.f;
#pragma unroll
    for (int t = 0; t < 8; ++t) {
      const float x = sv[lane + 64 * t];
      a0 = fmaf(gw1[(size_t)(row + 0) * DD + lane + 64 * t], x, a0);
      a1 = fmaf(gw1[(size_t)(row + 1) * DD + lane + 64 * t], x, a1);
      a2 = fmaf(gw1[(size_t)(row + 2) * DD + lane + 64 * t], x, a2);
      a3 = fmaf(gw1[(size_t)(row + 3) * DD + lane + 64 * t], x, a3);
    }
    a0 = wave_sum(a0); a1 = wave_sum(a1); a2 = wave_sum(a2); a3 = wave_sum(a3);
    if (lane == 0) {
      const float al = ga[0];
      float v0 = a0 + gb1[row + 0], v1 = a1 + gb1[row + 1];
      float v2 = a2 + gb1[row + 2], v3 = a3 + gb1[row + 3];
      tv[row + 0] = (v0 >= 0.f) ? v0 : al * v0;
      tv[row + 1] = (v1 >= 0.f) ? v1 : al * v1;
      tv[row + 2] = (v2 >= 0.f) ? v2 : al * v2;
      tv[row + 3] = (v3 >= 0.f) ? v3 : al * v3;
    }
  }
  __syncthreads();
  for (int rq = 0; rq < 8; ++rq) {  // phase 2: hv = gw2 @ tv + gb2
    const int row = w * 32 + rq * 4;
    float a0 = 0.f, a1 = 0.f, a2 = 0.f, a3 = 0.f;
#pragma unroll
    for (int t = 0; t < 8; ++t) {
      const float x = tv[lane + 64 * t];
      a0 = fmaf(gw2[(size_t)(row + 0) * DD + lane + 64 * t], x, a0);
      a1 = fmaf(gw2[(size_t)(row + 1) * DD + lane + 64 * t], x, a1);
      a2 = fmaf(gw2[(size_t)(row + 2) * DD + lane + 64 * t], x, a2);
      a3 = fmaf(gw2[(size_t)(row + 3) * DD + lane + 64 * t], x, a3);
    }
    a0 = wave_sum(a0); a1 = wave_sum(a1); a2 = wave_sum(a2); a3 = wave_sum(a3);
    if (lane == 0) {
      hv[row + 0] = a0 + gb2[row + 0];
      hv[row + 1] = a1 + gb2[row + 1];
      hv[row + 2] = a2 + gb2[row + 2];
      hv[row + 3] = a3 + gb2[row + 3];
    }
  }
  __syncthreads();
  for (int rq = 0; rq < 8; ++rq) {  // phase 3: summ = W @ hv
    const int row = w * 32 + rq * 4;
    float a0 = 0.f, a1 = 0.f, a2 = 0.f, a3 = 0.f;
#pragma unroll
    for (int t = 0; t < 8; ++t) {
      const float x = hv[lane + 64 * t];
      a0 = fmaf(W[(size_t)(row + 0) * DD + lane + 64 * t], x, a0);
      a1 = fmaf(W[(size_t)(row + 1) * DD + lane + 64 * t], x, a1);
      a2 = fmaf(W[(size_t)(row + 2) * DD + lane + 64 * t], x, a2);
      a3 = fmaf(W[(size_t)(row + 3) * DD + lane + 64 * t], x, a3);
    }
    a0 = wave_sum(a0); a1 = wave_sum(a1); a2 = wave_sum(a2); a3 = wave_sum(a3);
    if (lane == 0) {
      summ[row + 0] = a0;
      summ[row + 1] = a1;
      summ[row + 2] = a2;
      summ[row + 3] = a3;
    }
  }
}

// ------- node 6: paired sigmoid/log reduce -> per-block partials ------------
__global__ __launch_bounds__(256) void logsigp(
    const float* __restrict__ z1, const float* __restrict__ z2,
    const float* __restrict__ sm1, const float* __restrict__ sm2,
    float* __restrict__ plsP, float* __restrict__ plsN) {
  const int ch = blockIdx.y;
  const float* z = ch ? z2 : z1;
  const float* sp = ch ? sm2 : sm1;
  const float* sn = ch ? sm1 : sm2;
  const int lane = threadIdx.x & 63;
  const int wid = threadIdx.x >> 6;
  const int row = blockIdx.x * 4 + wid;
  float dp = 0.f, dn = 0.f;
#pragma unroll
  for (int t = 0; t < 8; ++t) {
    const float zv = z[(size_t)row * DD + lane + 64 * t];
    dp = fmaf(zv, sp[lane + 64 * t], dp);
    dn = fmaf(zv, sn[lane + 64 * t], dn);
  }
  dp = wave_sum(dp);
  dn = wave_sum(dn);
  __shared__ float bp[4], bn[4];
  if (lane == 0) {
    const float sg = 1.f / (1.f + __expf(-dp));
    bp[wid] = -logf(sg + EPSV);
    const float sg2 = 1.f / (1.f + __expf(-dn));
    bn[wid] = -logf(1.f - sg2 + EPSV);
  }
  __syncthreads();
  if (threadIdx.x == 0) {
    plsP[ch * 1024 + blockIdx.x] = bp[0] + bp[1] + bp[2] + bp[3];
    plsN[ch * 1024 + blockIdx.x] = bn[0] + bn[1] + bn[2] + bn[3];
  }
}

// ------- node 7: fused similarity (EXACT r2 body — 96 µs proven) ------------
// zb: [r11, r11m, r12, r12m, c12, c12m, c22, c22m] x NN.
__global__ __launch_bounds__(512) void sim_mfma(
    const u16* __restrict__ na, const u16* __restrict__ nb,
    const int* __restrict__ mask, float* __restrict__ zb) {
  extern __shared__ __align__(16) u16 shm[];  // 3 * 4 * 4096 u16 = 96 KiB
  const int tid = threadIdx.x;
  const int w = tid >> 6, lane = tid & 63;
  const int quad = lane >> 4, m16 = lane & 15;
  const int ig = w & 3, jh = w >> 2;
  const int i0 = blockIdx.y * 128, j0 = blockIdx.x * 128;
  const int roff =
      (m16 >> 1) * 64 + (((((m16 & 1) << 2) | quad) ^ (m16 >> 1)) * 8);
  const int st = (lane & 7) ^ (lane >> 3);
  const int srow = 2 * (lane >> 3) + (st >> 2);
  const int scol = (st & 3) * 8;
  const int p = w >> 1, rh = (w & 1) * 64;
  const u16* gs = (p & 1) ? nb : na;
  const int gr = ((p < 2) ? i0 : j0) + rh + srow;
  u16* dst0 = shm + p * 4096 + rh * 32;
  auto stage = [&](int bo, int k) {
    const int kn = k * 32;
#pragma unroll
    for (int rr = 0; rr < 64; rr += 16)
      gld16(&gs[(size_t)(gr + rr) * DD + kn + scol], dst0 + bo + rr * 32);
  };
  stage(0, 0);
  stage(16384, 1);
  bar_vm4();
  f32x4 a11[2][4] = {}, a12[2][4] = {}, a22[2][4] = {};
  int ro = 0;
  for (int kc = 0; kc < 16; ++kc) {
    if (kc <= 13) {
      int so = ro + 32768;
      if (so >= 49152) so -= 49152;
      stage(so, kc + 2);
    }
    const u16* Ai = shm + ro;
    const u16* Bi = shm + ro + 4096;
    const u16* Aj = shm + ro + 8192;
    const u16* Bj = shm + ro + 12288;
    short8 ai0 = *(const short8*)&Ai[(ig * 32) * 32 + roff];
    short8 ai1 = *(const short8*)&Ai[(ig * 32 + 16) * 32 + roff];
    short8 bi0 = *(const short8*)&Bi[(ig * 32) * 32 + roff];
    short8 bi1 = *(const short8*)&Bi[(ig * 32 + 16) * 32 + roff];
#pragma unroll
    for (int c = 0; c < 4; ++c) {
      short8 aj = *(const short8*)&Aj[(jh * 64 + c * 16) * 32 + roff];
      short8 bj = *(const short8*)&Bj[(jh * 64 + c * 16) * 32 + roff];
      __builtin_amdgcn_s_setprio(1);
      a11[0][c] = __builtin_amdgcn_mfma_f32_16x16x32_bf16(ai0, aj, a11[0][c], 0, 0, 0);
      a11[1][c] = __builtin_amdgcn_mfma_f32_16x16x32_bf16(ai1, aj, a11[1][c], 0, 0, 0);
      a12[0][c] = __builtin_amdgcn_mfma_f32_16x16x32_bf16(ai0, bj, a12[0][c], 0, 0, 0);
      a12[1][c] = __builtin_amdgcn_mfma_f32_16x16x32_bf16(ai1, bj, a12[1][c], 0, 0, 0);
      a22[0][c] = __builtin_amdgcn_mfma_f32_16x16x32_bf16(bi0, bj, a22[0][c], 0, 0, 0);
      a22[1][c] = __builtin_amdgcn_mfma_f32_16x16x32_bf16(bi1, bj, a22[1][c], 0, 0, 0);
      __builtin_amdgcn_s_setprio(0);
    }
    if (kc <= 13) bar_vm4();
    else if (kc == 14) bar_vm0();
    ro += 16384;
    if (ro == 49152) ro = 0;
  }
  float* rred = (float*)(shm + 16384);  // [4][128] row stats (buf1: dead)
  float* cred = rred + 512;             // [4][128] col stats
  rred[tid] = 0.f;
  rred[tid + 512] = 0.f;
  __syncthreads();
  float rs11[2][4] = {}, rm11[2][4] = {}, rs12[2][4] = {}, rm12[2][4] = {};
  float cs12[4] = {}, cm12[4] = {}, cs22[4] = {}, cm22[4] = {};
#pragma unroll
  for (int t = 0; t < 2; ++t)
#pragma unroll
    for (int c = 0; c < 4; ++c) {
      const int gj = j0 + jh * 64 + c * 16 + m16;
#pragma unroll
      for (int r = 0; r < 4; ++r) {
        const int gi = i0 + ig * 32 + t * 16 + quad * 4 + r;
        const float mv = (float)mask[(size_t)gi * NN + gj];
        const float e11 = __expf(a11[t][c][r] * INV_TAU);
        const float e12 = __expf(a12[t][c][r] * INV_TAU);
        const float e22 = __expf(a22[t][c][r] * INV_TAU);
        rs11[t][r] += e11;
        rm11[t][r] += e11 * mv;
        rs12[t][r] += e12;
        rm12[t][r] += e12 * mv;
        cs12[c] += e12;
        cm12[c] += e12 * mv;
        cs22[c] += e22;
        cm22[c] += e22 * mv;
      }
    }
#pragma unroll
  for (int t = 0; t < 2; ++t)
#pragma unroll
    for (int r = 0; r < 4; ++r) {
      float v0 = rs11[t][r], v1 = rm11[t][r], v2 = rs12[t][r], v3 = rm12[t][r];
#pragma unroll
      for (int o = 1; o < 16; o <<= 1) {
        v0 += __shfl_xor(v0, o, 64);
        v1 += __shfl_xor(v1, o, 64);
        v2 += __shfl_xor(v2, o, 64);
        v3 += __shfl_xor(v3, o, 64);
      }
      if (m16 == 0) {
        const int il = ig * 32 + t * 16 + quad * 4 + r;
        atomicAdd(&rred[0 * 128 + il], v0);
        atomicAdd(&rred[1 * 128 + il], v1);
        atomicAdd(&rred[2 * 128 + il], v2);
        atomicAdd(&rred[3 * 128 + il], v3);
      }
    }
#pragma unroll
  for (int c = 0; c < 4; ++c) {
    float v0 = cs12[c], v1 = cm12[c], v2 = cs22[c], v3 = cm22[c];
    v0 += __shfl_xor(v0, 16, 64); v0 += __shfl_xor(v0, 32, 64);
    v1 += __shfl_xor(v1, 16, 64); v1 += __shfl_xor(v1, 32, 64);
    v2 += __shfl_xor(v2, 16, 64); v2 += __shfl_xor(v2, 32, 64);
    v3 += __shfl_xor(v3, 16, 64); v3 += __shfl_xor(v3, 32, 64);
    if (lane < 16) {
      const int jl = jh * 64 + c * 16 + lane;
      atomicAdd(&cred[0 * 128 + jl], v0);
      atomicAdd(&cred[1 * 128 + jl], v1);
      atomicAdd(&cred[2 * 128 + jl], v2);
      atomicAdd(&cred[3 * 128 + jl], v3);
    }
  }
  __syncthreads();
  if (tid < 128) {
#pragma unroll
    for (int q = 0; q < 4; ++q)
      atomicAdd(&zb[q * NN + i0 + tid], rred[q * 128 + tid]);
  } else if (tid < 256) {
    const int jl = tid - 128;
#pragma unroll
    for (int q = 0; q < 4; ++q)
      atomicAdd(&zb[(4 + q) * NN + j0 + jl], cred[q * 128 + jl]);
  }
}

// ------- node 8: finalize (1 block): local InfoNCE + partial sums + combine -
__global__ __launch_bounds__(512) void fin(const float* __restrict__ zb,
                                           const float* __restrict__ plsP,
                                           const float* __restrict__ plsN,
                                           float* __restrict__ out) {
  const int tid = threadIdx.x;
  const int lane = tid & 63, w = tid >> 6;
  float S1 = 0.f, S2 = 0.f;
#pragma unroll
  for (int k = 0; k < 8; ++k) {
    const int i = tid + k * 512;
    const float r11 = zb[i], r11m = zb[NN + i];
    const float r12 = zb[2 * NN + i], r12m = zb[3 * NN + i];
    const float c12 = zb[4 * NN + i], c12m = zb[5 * NN + i];
    const float c22 = zb[6 * NN + i], c22m = zb[7 * NN + i];
    S1 += -logf(r12m / (r11 + r12 - r11m));
    S2 += -logf(c12m / (c22 + c12 - c22m));
  }
  float G = plsP[tid] + plsP[tid + 512] + plsP[tid + 1024] + plsP[tid + 1536] +
            plsN[tid] + plsN[tid + 512] + plsN[tid + 1024] + plsN[tid + 1536];
  S1 = wave_sum(S1);
  S2 = wave_sum(S2);
  G = wave_sum(G);
  __shared__ float fr[3][8];
  if (lane == 0) { fr[0][w] = S1; fr[1][w] = S2; fr[2][w] = G; }
  __syncthreads();
  if (tid == 0) {
    float s1t = 0.f, s2t = 0.f, gt = 0.f;
    for (int q = 0; q < 8; ++q) {
      s1t += fr[0][q];
      s2t += fr[1][q];
      gt += fr[2][q];
    }
    const float local = 0.5f * (s1t + s2t) * (1.f / NN);
    const float glob = 0.25f * gt * (1.f / NN);
    out[0] = 0.5f * local + 0.5f * glob;
  }
}

extern "C" void kernel_launch(void* const* d_in, const int* in_sizes, int n_in,
                              void* d_out, int out_size, void* d_ws,
                              size_t ws_size, hipStream_t stream) {
  const float* z1 = (const float*)d_in[0];
  const float* z2 = (const float*)d_in[1];
  const float* lw1 = (const float*)d_in[2];
  const float* lb1 = (const float*)d_in[3];
  const float* la = (const float*)d_in[4];
  const float* lw2 = (const float*)d_in[5];
  const float* lb2 = (const float*)d_in[6];
  const float* gw1 = (const float*)d_in[7];
  const float* gb1 = (const float*)d_in[8];
  const float* ga = (const float*)d_in[9];
  const float* gw2 = (const float*)d_in[10];
  const float* gb2 = (const float*)d_in[11];
  const float* W = (const float*)d_in[12];
  const int* mask = (const int*)d_in[13];
  float* out = (float*)d_out;

  static bool attr_set = false;
  if (!attr_set) {
    (void)hipFuncSetAttribute(reinterpret_cast<const void*>(sim_mfma),
                              hipFuncAttributeMaxDynamicSharedMemorySize,
                              98304);
    attr_set = true;
  }

  const size_t ND = (size_t)NN * DD;
  u16* W1b = (u16*)d_ws;                  // [512*512]
  u16* W2b = W1b + 512 * 512;             // [512*512]
  u16* Ab = W1b + 2 * 512 * 512;          // [2][N*D] bf16
  u16* Bb = Ab + 2 * ND;                  // [2][N*D] bf16
  float* zbf = (float*)(Bb + 2 * ND);     // 8*NN
  float* pc1 = zbf + 8 * NN;              // [128][512]
  float* pc2 = pc1 + 128 * 512;           // [128][512]
  float* summ1 = pc2 + 128 * 512;         // 512
  float* summ2 = summ1 + 512;             // 512
  float* plsP = summ2 + 512;              // 2048
  float* plsN = plsP + 2048;              // 2048

  dim3 blk(256);
  // 1) convert lw1|lw2|z1|z2 to bf16 + colmean partials + zero zbf
  tobf16cm<<<4736, blk, 0, stream>>>(lw1, lw2, z1, z2, W1b, pc1, pc2, zbf);
  // 2) layer-1 GEMM (PReLU): Ab -> Bb
  gemm_mfma<1><<<512, dim3(512), 0, stream>>>(Ab, W1b, lb1, la, Bb);
  // 3) layer-2 GEMM: Bb -> Ab
  gemm_mfma<0><<<512, dim3(512), 0, stream>>>(Bb, W2b, lb2, la, Ab);
  // 4) row L2-normalize: Ab -> Bb (na|nb)
  rownorm_bf16<<<2048, blk, 0, stream>>>(Ab, Bb);
  // 5) global projector chain (2 blocks, one per batch)
  mv_chain<<<2, dim3(1024), 0, stream>>>(pc1, pc2, gw1, gb1, ga, gw2, gb2, W,
                                         summ1, summ2);
  // 6) logsig partials (needs summ only)
  logsigp<<<dim3(1024, 2), blk, 0, stream>>>(z1, z2, summ1, summ2, plsP, plsN);
  // 7) fused similarity
  sim_mfma<<<dim3(32, 32), dim3(512), 98304, stream>>>(Bb, Bb + ND, mask, zbf);
  // 8) finalize -> out[0]
  fin<<<1, dim3(512), 0, stream>>>(zbf, plsP, plsN, out);
}

// Round 5
// 257.154 us; speedup vs baseline: 1.6605x; 1.1768x over previous
//
#include <hip/hip_runtime.h>
#include <math.h>

#define NN 4096
#define DD 512
#define INV_TAU 5.0f
#define EPSV 1e-15f

typedef unsigned short u16;
typedef __attribute__((ext_vector_type(8))) short short8;
typedef __attribute__((ext_vector_type(4))) float f32x4;

__device__ __forceinline__ void gld16(const void* g, void* l) {
  __builtin_amdgcn_global_load_lds(
      (const __attribute__((address_space(1))) unsigned int*)g,
      (__attribute__((address_space(3))) unsigned int*)l, 16, 0, 0);
}

// counted-vmcnt barriers (T3/T4)
__device__ __forceinline__ void bar_vm4() {
  asm volatile("s_waitcnt vmcnt(4) lgkmcnt(0)\n\ts_barrier" ::: "memory");
}
__device__ __forceinline__ void bar_vm2() {
  asm volatile("s_waitcnt vmcnt(2) lgkmcnt(0)\n\ts_barrier" ::: "memory");
}
__device__ __forceinline__ void bar_vm1() {
  asm volatile("s_waitcnt vmcnt(1) lgkmcnt(0)\n\ts_barrier" ::: "memory");
}
__device__ __forceinline__ void bar_vm0() {
  asm volatile("s_waitcnt vmcnt(0) lgkmcnt(0)\n\ts_barrier" ::: "memory");
}

__device__ __forceinline__ float bf2f(u16 u) {
  return __uint_as_float(((unsigned)u) << 16);
}
__device__ __forceinline__ u16 f2bf(float x) {  // RNE
  unsigned u = __float_as_uint(x);
  u += 0x7fff + ((u >> 16) & 1);
  return (u16)(u >> 16);
}

__device__ __forceinline__ float wave_sum(float v) {
#pragma unroll
  for (int o = 32; o > 0; o >>= 1) v += __shfl_down(v, o, 64);
  return v;
}

// ------- node 1: fp32->bf16 convert (lw1|lw2|z1|z2) + colmean partials -------
// blocks [0,4608): convert; blocks [4608,4736): column-sum partials of z1,z2
// (32 rows each -> pc[128][512], plain writes). blocks 0..127 zero zbf.
__global__ __launch_bounds__(256) void tobf16cm(
    const float* __restrict__ a, const float* __restrict__ b,
    const float* __restrict__ c, const float* __restrict__ d2,
    u16* __restrict__ o, float* __restrict__ pc1, float* __restrict__ pc2,
    float* __restrict__ zbf) {
  const int bid = blockIdx.x, tid = threadIdx.x;
  if (bid >= 4608) {  // colmean partials
    const int blk = bid - 4608;
    const int r0 = blk * 32;
    float a0 = 0.f, a1 = 0.f, c0 = 0.f, c1 = 0.f;
    for (int r = r0; r < r0 + 32; ++r) {
      const size_t ro = (size_t)r * DD;
      a0 += c[ro + tid];
      a1 += c[ro + 256 + tid];
      c0 += d2[ro + tid];
      c1 += d2[ro + 256 + tid];
    }
    pc1[blk * 512 + tid] = a0;
    pc1[blk * 512 + 256 + tid] = a1;
    pc2[blk * 512 + tid] = c0;
    pc2[blk * 512 + 256 + tid] = c1;
    return;
  }
  if (bid < 128) zbf[bid * 256 + tid] = 0.f;
  const int i = bid * 256 + tid;
  int j = i;
  const float* s;
  if (j < 65536) {
    s = a + (size_t)j * 4;
  } else {
    j -= 65536;
    if (j < 65536) {
      s = b + (size_t)j * 4;
    } else {
      j -= 65536;
      if (j < 524288) {
        s = c + (size_t)j * 4;
      } else {
        j -= 524288;
        s = d2 + (size_t)j * 4;
      }
    }
  }
  float4 v = *(const float4*)s;
  unsigned long long pk = (unsigned long long)f2bf(v.x) |
                          ((unsigned long long)f2bf(v.y) << 16) |
                          ((unsigned long long)f2bf(v.z) << 32) |
                          ((unsigned long long)f2bf(v.w) << 48);
  *(unsigned long long*)&o[(size_t)i * 4] = pk;
}

// ------- nodes 2-3: MFMA NT GEMM (proven) + leading mv blocks ---------------
// blocks [0,64): matvec phase (mv1: pc-reduce -> prelu(gw@sv+gb); mv2: gw@t+gb)
// blocks [64,576): the r2/r4-proven 128x64 depth-3 counted-vmcnt GEMM.
template <int ACT>
__global__ __launch_bounds__(512) void gemm_mv(
    const u16* __restrict__ A, const u16* __restrict__ Bw,
    const float* __restrict__ bias, const float* __restrict__ alpha_p,
    u16* __restrict__ out, const float* __restrict__ Mw,
    const float* __restrict__ mx1, const float* __restrict__ mx2,
    const float* __restrict__ mbias, const float* __restrict__ mal,
    float* __restrict__ my1, float* __restrict__ my2) {
  __shared__ __align__(16) u16 sh[3 * 6144];
  __shared__ float svb[512];
  const int tid = threadIdx.x, w = tid >> 6, lane = tid & 63;
  if (blockIdx.x < 64) {  // ---- mv block ----
    const int mb = blockIdx.x;
    const int bz = mb >> 5, bx = mb & 31;
    const float* xin = bz ? mx2 : mx1;
    float* y = bz ? my2 : my1;
    if (ACT) {  // mv1: reduce pc[128][512] -> sv
      float a = 0.f;
      for (int b = 0; b < 128; ++b) a += xin[b * 512 + tid];
      svb[tid] = a * (1.f / NN);
    } else {  // mv2: x = t vector
      svb[tid] = xin[tid];
    }
    __syncthreads();
#pragma unroll
    for (int rr = 0; rr < 2; ++rr) {
      const int row = bx * 16 + w * 2 + rr;
      float acc = 0.f;
#pragma unroll
      for (int q = 0; q < 8; ++q)
        acc = fmaf(Mw[(size_t)row * DD + lane + 64 * q], svb[lane + 64 * q],
                   acc);
      acc = wave_sum(acc);
      if (lane == 0) {
        acc += mbias[row];
        if (ACT) {
          const float al = mal[0];
          acc = (acc >= 0.f) ? acc : al * acc;
        }
        y[row] = acc;
      }
    }
    return;
  }
  // ---- GEMM block (bid2 in [0,512)) ----
  const int quad = lane >> 4, m16 = lane & 15;
  const int wi = w >> 1, wj = w & 1;
  const int bid2 = blockIdx.x - 64;
  const int xcd = bid2 & 7, idx = bid2 >> 3;
  const int i0 = (4 * xcd + (idx & 3)) * 128;
  const int j0 = ((idx >> 2) & 7) * 64;
  const int bz = idx >> 5;
  const u16* Ab = A + (size_t)bz * ((size_t)NN * DD);
  u16* ob = out + (size_t)bz * ((size_t)NN * DD);
  const int roff =
      (m16 >> 1) * 64 + (((((m16 & 1) << 2) | quad) ^ (m16 >> 1)) * 8);
  const int st = (lane & 7) ^ (lane >> 3);
  const int srow = 2 * (lane >> 3) + (st >> 2);
  const int scol = (st & 3) * 8;
  const u16* gs = (w < 4) ? Ab : Bw;
  const int grow0 = ((w < 4) ? i0 + 2 * w * 16 : j0 + (w - 4) * 16) + srow;
  const int doff0 = (w < 4) ? 2 * w * 512 : 4096 + (w - 4) * 512;
  auto stage = [&](int bo, int k) {
    const int kn = k * 32;
    gld16(&gs[(size_t)grow0 * DD + kn + scol], sh + bo + doff0);
    if (w < 4)
      gld16(&gs[(size_t)(grow0 + 16) * DD + kn + scol], sh + bo + doff0 + 512);
  };
  stage(0, 0);
  stage(6144, 1);
  if (w < 4) bar_vm2(); else bar_vm1();
  f32x4 acc[2][2] = {};
  int ro = 0;
  for (int kc = 0; kc < 16; ++kc) {
    if (kc <= 13) {
      int so = ro + 12288;
      if (so >= 18432) so -= 18432;
      stage(so, kc + 2);
    }
    const u16* As = sh + ro;
    const u16* Bs = sh + ro + 4096;
    short8 ar[2], br[2];
#pragma unroll
    for (int s = 0; s < 2; ++s) {
      ar[s] = *(const short8*)&As[(wi * 32 + s * 16) * 32 + roff];
      br[s] = *(const short8*)&Bs[(wj * 32 + s * 16) * 32 + roff];
    }
    __builtin_amdgcn_s_setprio(1);
#pragma unroll
    for (int si = 0; si < 2; ++si)
#pragma unroll
      for (int sj = 0; sj < 2; ++sj)
        acc[si][sj] = __builtin_amdgcn_mfma_f32_16x16x32_bf16(
            ar[si], br[sj], acc[si][sj], 0, 0, 0);
    __builtin_amdgcn_s_setprio(0);
    if (kc <= 13) {
      if (w < 4) bar_vm2(); else bar_vm1();
    } else if (kc == 14) {
      bar_vm0();
    }
    ro += 6144;
    if (ro == 18432) ro = 0;
  }
  const float al = ACT ? alpha_p[0] : 0.f;
#pragma unroll
  for (int si = 0; si < 2; ++si)
#pragma unroll
    for (int sj = 0; sj < 2; ++sj) {
      const int col = j0 + wj * 32 + sj * 16 + m16;
      const float bv = bias[col];
#pragma unroll
      for (int r = 0; r < 4; ++r) {
        const int row = i0 + wi * 32 + si * 16 + quad * 4 + r;
        float x = acc[si][sj][r] + bv;
        if (ACT) x = (x >= 0.f) ? x : al * x;
        ob[(size_t)row * DD + col] = f2bf(x);
      }
    }
}

// ------- node 4: row L2-normalize (proven r2) + leading mv3 blocks ----------
// blocks [0,256): summ = W @ hg (one wave per row); blocks [256,2304): rownorm.
__global__ __launch_bounds__(256) void rownorm_mv(
    const u16* __restrict__ h, u16* __restrict__ o,
    const float* __restrict__ W, const float* __restrict__ hx1,
    const float* __restrict__ hx2, float* __restrict__ sm1,
    float* __restrict__ sm2) {
  const int bid = blockIdx.x, tid = threadIdx.x;
  const int lane = tid & 63, w = tid >> 6;
  if (bid < 256) {  // mv3
    const int bz = bid >> 7, bx = bid & 127;
    const float* x = bz ? hx2 : hx1;
    float* y = bz ? sm2 : sm1;
    const int row = bx * 4 + w;
    float acc = 0.f;
#pragma unroll
    for (int q = 0; q < 8; ++q)
      acc = fmaf(W[(size_t)row * DD + lane + 64 * q], x[lane + 64 * q], acc);
    acc = wave_sum(acc);
    if (lane == 0) y[row] = acc;
    return;
  }
  const int row = (bid - 256) * 4 + w;
  const size_t base = (size_t)row * DD + lane * 8;
  short8 v = *(const short8*)&h[base];
  float f[8];
  float s = 0.f;
#pragma unroll
  for (int j = 0; j < 8; ++j) {
    f[j] = bf2f((u16)v[j]);
    s += f[j] * f[j];
  }
  s = wave_sum(s);
  const float inv = 1.f / fmaxf(sqrtf(__shfl(s, 0, 64)), 1e-12f);
  short8 r;
#pragma unroll
  for (int j = 0; j < 8; ++j) r[j] = (short)f2bf(f[j] * inv);
  *(short8*)&o[base] = r;
}

// ------- node 5: fused similarity (EXACT r2/r4 body) + leading logsig rows --
// grid (32, 34): by<2 -> logsig partial blocks (64); by>=2 -> sim with
// i0=(by-2)*128. zb: [r11,r11m,r12,r12m,c12,c12m,c22,c22m] x NN.
__global__ __launch_bounds__(512) void sim_mfma(
    const u16* __restrict__ na, const u16* __restrict__ nb,
    const int* __restrict__ mask, float* __restrict__ zb,
    const float* __restrict__ z1g, const float* __restrict__ z2g,
    const float* __restrict__ sm1, const float* __restrict__ sm2,
    float* __restrict__ plsP, float* __restrict__ plsN) {
  extern __shared__ __align__(16) u16 shm[];  // 96 KiB dynamic
  const int tid = threadIdx.x;
  const int w = tid >> 6, lane = tid & 63;
  if (blockIdx.y < 2) {  // ---- logsig partials: 64 blocks ----
    const int lx = blockIdx.y * 32 + blockIdx.x;
    const int bz = lx >> 5, bx5 = lx & 31;
    const float* z = bz ? z2g : z1g;
    const float* sp = bz ? sm2 : sm1;
    const float* sn = bz ? sm1 : sm2;
    float lp = 0.f, ln_ = 0.f;
    for (int k = 0; k < 16; ++k) {
      const int row = bx5 * 128 + w * 16 + k;
      float dp = 0.f, dn = 0.f;
#pragma unroll
      for (int t = 0; t < 8; ++t) {
        const float zv = z[(size_t)row * DD + lane + 64 * t];
        dp = fmaf(zv, sp[lane + 64 * t], dp);
        dn = fmaf(zv, sn[lane + 64 * t], dn);
      }
      dp = wave_sum(dp);
      dn = wave_sum(dn);
      if (lane == 0) {
        lp += -logf(1.f / (1.f + __expf(-dp)) + EPSV);
        ln_ += -logf(1.f - 1.f / (1.f + __expf(-dn)) + EPSV);
      }
    }
    float* red = (float*)shm;
    if (lane == 0) { red[w] = lp; red[8 + w] = ln_; }
    __syncthreads();
    if (tid == 0) {
      float sP = 0.f, sN = 0.f;
      for (int q = 0; q < 8; ++q) { sP += red[q]; sN += red[8 + q]; }
      plsP[lx] = sP;
      plsN[lx] = sN;
    }
    return;
  }
  const int quad = lane >> 4, m16 = lane & 15;
  const int ig = w & 3, jh = w >> 2;
  const int i0 = (blockIdx.y - 2) * 128, j0 = blockIdx.x * 128;
  const int roff =
      (m16 >> 1) * 64 + (((((m16 & 1) << 2) | quad) ^ (m16 >> 1)) * 8);
  const int st = (lane & 7) ^ (lane >> 3);
  const int srow = 2 * (lane >> 3) + (st >> 2);
  const int scol = (st & 3) * 8;
  const int p = w >> 1, rh = (w & 1) * 64;
  const u16* gs = (p & 1) ? nb : na;
  const int gr = ((p < 2) ? i0 : j0) + rh + srow;
  u16* dst0 = shm + p * 4096 + rh * 32;
  auto stage = [&](int bo, int k) {
    const int kn = k * 32;
#pragma unroll
    for (int rr = 0; rr < 64; rr += 16)
      gld16(&gs[(size_t)(gr + rr) * DD + kn + scol], dst0 + bo + rr * 32);
  };
  stage(0, 0);
  stage(16384, 1);
  bar_vm4();
  f32x4 a11[2][4] = {}, a12[2][4] = {}, a22[2][4] = {};
  int ro = 0;
  for (int kc = 0; kc < 16; ++kc) {
    if (kc <= 13) {
      int so = ro + 32768;
      if (so >= 49152) so -= 49152;
      stage(so, kc + 2);
    }
    const u16* Ai = shm + ro;
    const u16* Bi = shm + ro + 4096;
    const u16* Aj = shm + ro + 8192;
    const u16* Bj = shm + ro + 12288;
    short8 ai0 = *(const short8*)&Ai[(ig * 32) * 32 + roff];
    short8 ai1 = *(const short8*)&Ai[(ig * 32 + 16) * 32 + roff];
    short8 bi0 = *(const short8*)&Bi[(ig * 32) * 32 + roff];
    short8 bi1 = *(const short8*)&Bi[(ig * 32 + 16) * 32 + roff];
#pragma unroll
    for (int c = 0; c < 4; ++c) {
      short8 aj = *(const short8*)&Aj[(jh * 64 + c * 16) * 32 + roff];
      short8 bj = *(const short8*)&Bj[(jh * 64 + c * 16) * 32 + roff];
      __builtin_amdgcn_s_setprio(1);
      a11[0][c] = __builtin_amdgcn_mfma_f32_16x16x32_bf16(ai0, aj, a11[0][c], 0, 0, 0);
      a11[1][c] = __builtin_amdgcn_mfma_f32_16x16x32_bf16(ai1, aj, a11[1][c], 0, 0, 0);
      a12[0][c] = __builtin_amdgcn_mfma_f32_16x16x32_bf16(ai0, bj, a12[0][c], 0, 0, 0);
      a12[1][c] = __builtin_amdgcn_mfma_f32_16x16x32_bf16(ai1, bj, a12[1][c], 0, 0, 0);
      a22[0][c] = __builtin_amdgcn_mfma_f32_16x16x32_bf16(bi0, bj, a22[0][c], 0, 0, 0);
      a22[1][c] = __builtin_amdgcn_mfma_f32_16x16x32_bf16(bi1, bj, a22[1][c], 0, 0, 0);
      __builtin_amdgcn_s_setprio(0);
    }
    if (kc <= 13) bar_vm4();
    else if (kc == 14) bar_vm0();
    ro += 16384;
    if (ro == 49152) ro = 0;
  }
  float* rred = (float*)(shm + 16384);  // [4][128] row stats (buf1: dead)
  float* cred = rred + 512;             // [4][128] col stats
  rred[tid] = 0.f;
  rred[tid + 512] = 0.f;
  __syncthreads();
  float rs11[2][4] = {}, rm11[2][4] = {}, rs12[2][4] = {}, rm12[2][4] = {};
  float cs12[4] = {}, cm12[4] = {}, cs22[4] = {}, cm22[4] = {};
#pragma unroll
  for (int t = 0; t < 2; ++t)
#pragma unroll
    for (int c = 0; c < 4; ++c) {
      const int gj = j0 + jh * 64 + c * 16 + m16;
#pragma unroll
      for (int r = 0; r < 4; ++r) {
        const int gi = i0 + ig * 32 + t * 16 + quad * 4 + r;
        const float mv = (float)mask[(size_t)gi * NN + gj];
        const float e11 = __expf(a11[t][c][r] * INV_TAU);
        const float e12 = __expf(a12[t][c][r] * INV_TAU);
        const float e22 = __expf(a22[t][c][r] * INV_TAU);
        rs11[t][r] += e11;
        rm11[t][r] += e11 * mv;
        rs12[t][r] += e12;
        rm12[t][r] += e12 * mv;
        cs12[c] += e12;
        cm12[c] += e12 * mv;
        cs22[c] += e22;
        cm22[c] += e22 * mv;
      }
    }
#pragma unroll
  for (int t = 0; t < 2; ++t)
#pragma unroll
    for (int r = 0; r < 4; ++r) {
      float v0 = rs11[t][r], v1 = rm11[t][r], v2 = rs12[t][r], v3 = rm12[t][r];
#pragma unroll
      for (int o = 1; o < 16; o <<= 1) {
        v0 += __shfl_xor(v0, o, 64);
        v1 += __shfl_xor(v1, o, 64);
        v2 += __shfl_xor(v2, o, 64);
        v3 += __shfl_xor(v3, o, 64);
      }
      if (m16 == 0) {
        const int il = ig * 32 + t * 16 + quad * 4 + r;
        atomicAdd(&rred[0 * 128 + il], v0);
        atomicAdd(&rred[1 * 128 + il], v1);
        atomicAdd(&rred[2 * 128 + il], v2);
        atomicAdd(&rred[3 * 128 + il], v3);
      }
    }
#pragma unroll
  for (int c = 0; c < 4; ++c) {
    float v0 = cs12[c], v1 = cm12[c], v2 = cs22[c], v3 = cm22[c];
    v0 += __shfl_xor(v0, 16, 64); v0 += __shfl_xor(v0, 32, 64);
    v1 += __shfl_xor(v1, 16, 64); v1 += __shfl_xor(v1, 32, 64);
    v2 += __shfl_xor(v2, 16, 64); v2 += __shfl_xor(v2, 32, 64);
    v3 += __shfl_xor(v3, 16, 64); v3 += __shfl_xor(v3, 32, 64);
    if (lane < 16) {
      const int jl = jh * 64 + c * 16 + lane;
      atomicAdd(&cred[0 * 128 + jl], v0);
      atomicAdd(&cred[1 * 128 + jl], v1);
      atomicAdd(&cred[2 * 128 + jl], v2);
      atomicAdd(&cred[3 * 128 + jl], v3);
    }
  }
  __syncthreads();
  if (tid < 128) {
#pragma unroll
    for (int q = 0; q < 4; ++q)
      atomicAdd(&zb[q * NN + i0 + tid], rred[q * 128 + tid]);
  } else if (tid < 256) {
    const int jl = tid - 128;
#pragma unroll
    for (int q = 0; q < 4; ++q)
      atomicAdd(&zb[(4 + q) * NN + j0 + jl], cred[q * 128 + jl]);
  }
}

// ------- node 6: finalize (1 block): local InfoNCE + partial sums + combine -
__global__ __launch_bounds__(512) void fin(const float* __restrict__ zb,
                                           const float* __restrict__ plsP,
                                           const float* __restrict__ plsN,
                                           float* __restrict__ out) {
  const int tid = threadIdx.x;
  const int lane = tid & 63, w = tid >> 6;
  float S1 = 0.f, S2 = 0.f;
#pragma unroll
  for (int k = 0; k < 8; ++k) {
    const int i = tid + k * 512;
    const float r11 = zb[i], r11m = zb[NN + i];
    const float r12 = zb[2 * NN + i], r12m = zb[3 * NN + i];
    const float c12 = zb[4 * NN + i], c12m = zb[5 * NN + i];
    const float c22 = zb[6 * NN + i], c22m = zb[7 * NN + i];
    S1 += -logf(r12m / (r11 + r12 - r11m));
    S2 += -logf(c12m / (c22 + c12 - c22m));
  }
  float G = (tid < 64) ? (plsP[tid] + plsN[tid]) : 0.f;
  S1 = wave_sum(S1);
  S2 = wave_sum(S2);
  G = wave_sum(G);
  __shared__ float fr[3][8];
  if (lane == 0) { fr[0][w] = S1; fr[1][w] = S2; fr[2][w] = G; }
  __syncthreads();
  if (tid == 0) {
    float s1t = 0.f, s2t = 0.f, gt = 0.f;
    for (int q = 0; q < 8; ++q) {
      s1t += fr[0][q];
      s2t += fr[1][q];
      gt += fr[2][q];
    }
    const float local = 0.5f * (s1t + s2t) * (1.f / NN);
    const float glob = 0.25f * gt * (1.f / NN);
    out[0] = 0.5f * local + 0.5f * glob;
  }
}

extern "C" void kernel_launch(void* const* d_in, const int* in_sizes, int n_in,
                              void* d_out, int out_size, void* d_ws,
                              size_t ws_size, hipStream_t stream) {
  const float* z1 = (const float*)d_in[0];
  const float* z2 = (const float*)d_in[1];
  const float* lw1 = (const float*)d_in[2];
  const float* lb1 = (const float*)d_in[3];
  const float* la = (const float*)d_in[4];
  const float* lw2 = (const float*)d_in[5];
  const float* lb2 = (const float*)d_in[6];
  const float* gw1 = (const float*)d_in[7];
  const float* gb1 = (const float*)d_in[8];
  const float* ga = (const float*)d_in[9];
  const float* gw2 = (const float*)d_in[10];
  const float* gb2 = (const float*)d_in[11];
  const float* W = (const float*)d_in[12];
  const int* mask = (const int*)d_in[13];
  float* out = (float*)d_out;

  static bool attr_set = false;
  if (!attr_set) {
    (void)hipFuncSetAttribute(reinterpret_cast<const void*>(sim_mfma),
                              hipFuncAttributeMaxDynamicSharedMemorySize,
                              98304);
    attr_set = true;
  }

  const size_t ND = (size_t)NN * DD;
  u16* W1b = (u16*)d_ws;                  // [512*512]
  u16* W2b = W1b + 512 * 512;             // [512*512]
  u16* Ab = W1b + 2 * 512 * 512;          // [2][N*D] bf16
  u16* Bb = Ab + 2 * ND;                  // [2][N*D] bf16
  float* zbf = (float*)(Bb + 2 * ND);     // 8*NN
  float* pc1 = zbf + 8 * NN;              // [128][512]
  float* pc2 = pc1 + 128 * 512;           // [128][512]
  float* t1 = pc2 + 128 * 512;            // 512
  float* t2 = t1 + 512;                   // 512
  float* hg1 = t2 + 512;                  // 512
  float* hg2 = hg1 + 512;                 // 512
  float* summ1 = hg2 + 512;               // 512
  float* summ2 = summ1 + 512;             // 512
  float* plsP = summ2 + 512;              // 64
  float* plsN = plsP + 64;                // 64

  // 1) convert lw1|lw2|z1|z2 to bf16 + colmean partials + zero zbf
  tobf16cm<<<4736, dim3(256), 0, stream>>>(lw1, lw2, z1, z2, W1b, pc1, pc2,
                                           zbf);
  // 2) layer-1 GEMM (PReLU) + mv1 (pc -> t)
  gemm_mv<1><<<576, dim3(512), 0, stream>>>(Ab, W1b, lb1, la, Bb, gw1, pc1,
                                            pc2, gb1, ga, t1, t2);
  // 3) layer-2 GEMM + mv2 (t -> hg)
  gemm_mv<0><<<576, dim3(512), 0, stream>>>(Bb, W2b, lb2, la, Ab, gw2, t1, t2,
                                            gb2, nullptr, hg1, hg2);
  // 4) row L2-normalize + mv3 (hg -> summ)
  rownorm_mv<<<2304, dim3(256), 0, stream>>>(Ab, Bb, W, hg1, hg2, summ1,
                                             summ2);
  // 5) fused similarity + logsig partials (leading 64 blocks)
  sim_mfma<<<dim3(32, 34), dim3(512), 98304, stream>>>(
      Bb, Bb + ND, mask, zbf, z1, z2, summ1, summ2, plsP, plsN);
  // 6) finalize -> out[0]
  fin<<<1, dim3(512), 0, stream>>>(zbf, plsP, plsN, out);
}